// Round 6
// baseline (225.191 us; speedup 1.0000x reference)
//
#include <hip/hip_runtime.h>
#include <hip/hip_bf16.h>
#include <math.h>

typedef __attribute__((ext_vector_type(8))) short short8;
typedef __attribute__((ext_vector_type(4))) short s16x4;
typedef __attribute__((ext_vector_type(4))) float f32x4;

#define SEQ 2048
#define DH 128

__device__ __forceinline__ short f2bf(float f) {
    union { float f; unsigned u; } v; v.f = f;
    unsigned r = v.u + 0x7fffu + ((v.u >> 16) & 1u);
    return (short)(r >> 16);
}
__device__ __forceinline__ float bf2f(short s) {
    union { unsigned u; float f; } v; v.u = ((unsigned)(unsigned short)s) << 16;
    return v.f;
}

__device__ __forceinline__ void gll16(const void* g, void* l) {
    __builtin_amdgcn_global_load_lds(
        (const __attribute__((address_space(1))) unsigned int*)g,
        (__attribute__((address_space(3))) unsigned int*)l, 16, 0, 0);
}

// ---------------- Wt2: frag-linear bf16 W ----------------
__global__ __launch_bounds__(256) void wt_kernel(
    const float* __restrict__ Wq, const float* __restrict__ Wk, const float* __restrict__ Wv,
    short* __restrict__ Wt2)
{
    const int t = threadIdx.x;
    const int m  = blockIdx.x >> 4;
    const int ks = blockIdx.x & 15;
    const float* W = m == 0 ? Wq : (m == 1 ? Wk : Wv);
    short* dst = Wt2 + ((size_t)(m * 16 + ks) * 1024) * 8;
    #pragma unroll
    for (int j = 0; j < 4; j++) {
        const int idx = t * 4 + j;
        const int ctile = idx >> 7;
        const int kc = (idx >> 6) & 1;
        const int gg = (idx >> 4) & 3;
        const int cc = idx & 15;
        const int col = ctile * 16 + cc;
        const int kb = ks * 64 + kc * 32 + gg * 8;
        short8 h;
        #pragma unroll
        for (int e = 0; e < 8; e++) h[e] = f2bf(W[(size_t)(kb + e) * 128 + col]);
        *(short8*)&dst[idx * 8] = h;
    }
}

// ---------------- proj: Qh,Kh,Vh (bf16) = x @ W, tiled MFMA ----------------
__global__ __launch_bounds__(256) void proj_kernel(
    const float* __restrict__ x, const short* __restrict__ Wt2,
    short* __restrict__ Qh, short* __restrict__ Kh, short* __restrict__ Vh)
{
    __shared__ short Xs[2048];
    __shared__ short Ws[8192];
    const int t = threadIdx.x;
    const int w = t >> 6, l = t & 63;
    const int c = l & 15, g = l >> 4;
    const int bid = blockIdx.x;
    const int m = bid % 3;
    const int row0 = (bid / 3) * 32;
    const short* Wm = Wt2 + (size_t)m * 16 * 1024 * 8;

    const int xr = t >> 3;
    const int xk = (t & 7) * 8;
    const int xIdx = ((xr >> 4) * 2 + (xk >> 5)) * 64 + ((xk >> 3) & 3) * 16 + (xr & 15);

    const int rt = w & 1;
    const int ct4 = (w >> 1) * 4;
    f32x4 acc[4];
    #pragma unroll
    for (int nt = 0; nt < 4; nt++) acc[nt] = (f32x4)0.f;

    for (int ks = 0; ks < 16; ks++) {
        __syncthreads();
        const short* wsrc = Wm + ((size_t)ks * 1024 + w * 256 + l) * 8;
        #pragma unroll
        for (int j = 0; j < 4; j++)
            gll16(wsrc + j * 64 * 8, (void*)&Ws[(w * 256 + j * 64) * 8]);
        {
            const float* xp = &x[(size_t)(row0 + xr) * 1024 + ks * 64 + xk];
            const float4 a = *(const float4*)xp;
            const float4 b = *(const float4*)(xp + 4);
            short8 h;
            h[0] = f2bf(a.x); h[1] = f2bf(a.y); h[2] = f2bf(a.z); h[3] = f2bf(a.w);
            h[4] = f2bf(b.x); h[5] = f2bf(b.y); h[6] = f2bf(b.z); h[7] = f2bf(b.w);
            *(short8*)&Xs[xIdx * 8] = h;
        }
        __syncthreads();
        #pragma unroll
        for (int kc = 0; kc < 2; kc++) {
            const short8 af = *(const short8*)&Xs[((rt * 2 + kc) * 64 + l) * 8];
            #pragma unroll
            for (int nt = 0; nt < 4; nt++) {
                const short8 bf = *(const short8*)&Ws[(((ct4 + nt) * 2 + kc) * 64 + l) * 8];
                acc[nt] = __builtin_amdgcn_mfma_f32_16x16x32_bf16(af, bf, acc[nt], 0, 0, 0);
            }
        }
    }
    short* Out = m == 0 ? Qh : (m == 1 ? Kh : Vh);
    #pragma unroll
    for (int nt = 0; nt < 4; nt++)
        #pragma unroll
        for (int r = 0; r < 4; r++)
            Out[(size_t)(row0 + rt * 16 + 4 * g + r) * 128 + (ct4 + nt) * 16 + c] = f2bf(acc[nt][r]);
}

// ---------------- y = K @ L (f32 acc), Yh bf16 + SQ from rounded y ----------------
__global__ __launch_bounds__(256) void y_kernel(
    const short* __restrict__ Kh, const float* __restrict__ L,
    short* __restrict__ Yh, float* __restrict__ SQ)
{
    __shared__ float Ls[128 * 128];
    __shared__ short Ks[16][128];
    const int t = threadIdx.x;
    const int row0 = blockIdx.x * 16;
    #pragma unroll
    for (int j = 0; j < 16; j++) {
        int lin = t + j * 256;
        ((float4*)Ls)[lin] = ((const float4*)L)[lin];
    }
    {
        int r = t >> 4, ch = t & 15;
        *(short8*)&Ks[r][ch * 8] = *(const short8*)&Kh[(size_t)(row0 + r) * 128 + ch * 8];
    }
    __syncthreads();
    const int rl = t >> 4, c4 = (t & 15) * 4;
    float acc[8] = {};
    for (int d = 0; d < 128; d++) {
        const float kd = bf2f(Ks[rl][d]);
        const float4 l0 = *(const float4*)&Ls[d * 128 + c4];
        const float4 l1 = *(const float4*)&Ls[d * 128 + c4 + 64];
        acc[0] += kd * l0.x; acc[1] += kd * l0.y; acc[2] += kd * l0.z; acc[3] += kd * l0.w;
        acc[4] += kd * l1.x; acc[5] += kd * l1.y; acc[6] += kd * l1.z; acc[7] += kd * l1.w;
    }
    const int row = row0 + rl;
    s16x4 h0, h1;
    float s = 0.f;
    #pragma unroll
    for (int j = 0; j < 4; j++) {
        short h = f2bf(acc[j]);     float rv = bf2f(h); s += rv * rv; h0[j] = h;
        short g = f2bf(acc[j + 4]); float gv = bf2f(g); s += gv * gv; h1[j] = g;
    }
    *(s16x4*)&Yh[(size_t)row * 128 + c4]      = h0;
    *(s16x4*)&Yh[(size_t)row * 128 + c4 + 64] = h1;
    for (int off = 1; off < 16; off <<= 1) s += __shfl_xor(s, off);
    if ((t & 15) == 0) SQ[row] = s;
}

// ---------------- Vt[b][d 128][key 2048] = Vh[b][key][d] ----------------
__global__ __launch_bounds__(256) void vt_kernel(
    const short* __restrict__ Vh, short* __restrict__ Vt)
{
    __shared__ short Ls[64][72];
    const int t = threadIdx.x;
    const int b  = blockIdx.x >> 6;
    const int nb = (blockIdx.x >> 1) & 31;
    const int db = blockIdx.x & 1;
    const int n0 = nb * 64, d0 = db * 64;
    const short* Vb = Vh + (size_t)b * SEQ * 128;
    short* Vtb = Vt + (size_t)b * 128 * SEQ;
    #pragma unroll
    for (int i = 0; i < 2; i++) {
        int row = (t >> 3) + 32 * i;
        int ch = t & 7;
        *(short8*)&Ls[row][ch * 8] = *(const short8*)&Vb[(size_t)(n0 + row) * 128 + d0 + ch * 8];
    }
    __syncthreads();
    #pragma unroll
    for (int i = 0; i < 2; i++) {
        int dd = (t >> 3) + 32 * i;
        int nc = t & 7;
        short8 v;
        #pragma unroll
        for (int j = 0; j < 8; j++) v[j] = Ls[nc * 8 + j][dd];
        *(short8*)&Vtb[(size_t)(d0 + dd) * SEQ + n0 + nc * 8] = v;
    }
}

// ---------------- fused dual attention, MFMA, no global atomics ----------------
// 512 blocks = grav(2) x b(4) x qt(64, LPT order), 8 waves each (16 waves/CU).
// Waves split key-tiles stride 8; merge via LDS ds_add_f32; block owns output.
// No explicit fences: P slice is wave-private, compiler lgkmcnt tracking
// suffices and the scheduler is free to hoist V/B loads under exp/VALU.
__global__ __launch_bounds__(512, 4) void attn_kernel(
    const short* __restrict__ Qh, const short* __restrict__ Kh,
    const short* __restrict__ Yh, const short* __restrict__ Vt,
    const float* __restrict__ SQv,
    float* __restrict__ OL, float* __restrict__ OG,
    float* __restrict__ LS, float* __restrict__ GS)
{
    __shared__ short P[8 * 2048];       // per-wave 4 KB swizzled P slices
    __shared__ float Obuf[32][132];     // f32 merge buffer (stride 132: free 2-way)
    __shared__ float Rs[32];
    const int t = threadIdx.x;
    const int w = t >> 6, l = t & 63;
    const int c = l & 15, g = l >> 4;
    const int bid = blockIdx.x;
    const int qt = 63 - (bid >> 3);     // heavy tiles dispatch first (LPT)
    const int b = bid & 3;
    const int grav = (bid >> 2) & 1;
    const int q0 = qt * 32;
    const int nkt = (qt + 2) >> 1;      // # 64-key tiles

    for (int i = t; i < 32 * 132; i += 512) ((float*)Obuf)[i] = 0.f;
    if (t < 32) Rs[t] = 0.f;
    __syncthreads();

    const size_t boff = (size_t)b * SEQ * 128;
    const short* Ab = (grav ? Yh : Qh) + boff;
    const short* Bb = (grav ? Yh : Kh) + boff;
    const short* Vb = Vt + boff;
    const float* SQb = SQv + b * SEQ;
    short* Pw = P + w * 2048;

    short8 qf[2][4];
    #pragma unroll
    for (int mt = 0; mt < 2; mt++)
        #pragma unroll
        for (int kc = 0; kc < 4; kc++)
            qf[mt][kc] = *(const short8*)&Ab[(size_t)(q0 + mt * 16 + c) * 128 + kc * 32 + 8 * g];

    float sqq[2][4];
    if (grav) {
        #pragma unroll
        for (int mt = 0; mt < 2; mt++)
            #pragma unroll
            for (int r = 0; r < 4; r++)
                sqq[mt][r] = SQb[q0 + mt * 16 + 4 * g + r];
    }

    f32x4 acc[2][8];
    #pragma unroll
    for (int mt = 0; mt < 2; mt++)
        #pragma unroll
        for (int dt = 0; dt < 8; dt++) acc[mt][dt] = (f32x4)0.f;
    float rsum[2][4] = {};

    // exp(s/sqrt(128)) = 2^(s*0.12751743); exp(-d2/256) = 2^(-d2*0.005635527)
    const float CL = 0.12751743f;
    const float CG = -0.0056355275f;

    for (int tt = w; tt < nkt; tt += 8) {
        const int k0 = tt * 64;
        #pragma unroll
        for (int kt = 0; kt < 4; kt++) {
            const int kbase = k0 + kt * 16;
            if (kbase <= q0 + 31) {
                short8 bf[4];
                #pragma unroll
                for (int kc = 0; kc < 4; kc++)
                    bf[kc] = *(const short8*)&Bb[(size_t)(kbase + c) * 128 + kc * 32 + 8 * g];
                const float sqk = grav ? SQb[kbase + c] : 0.f;
                #pragma unroll
                for (int mt = 0; mt < 2; mt++) {
                    f32x4 sc = (f32x4)0.f;
                    #pragma unroll
                    for (int kc = 0; kc < 4; kc++)
                        sc = __builtin_amdgcn_mfma_f32_16x16x32_bf16(qf[mt][kc], bf[kc], sc, 0, 0, 0);
                    #pragma unroll
                    for (int r = 0; r < 4; r++) {
                        const int qrow = q0 + mt * 16 + 4 * g + r;
                        const int key = kbase + c;
                        float p = 0.f;
                        if (key <= qrow) {
                            if (grav) {
                                float d2 = sqq[mt][r] + sqk - 2.f * sc[r];
                                d2 = fmaxf(d2, 0.f);
                                p = __builtin_amdgcn_exp2f(d2 * CG);
                            } else {
                                p = __builtin_amdgcn_exp2f(sc[r] * CL);
                            }
                        }
                        const short ph = f2bf(p);
                        rsum[mt][r] += bf2f(ph);
                        const int row = mt * 16 + 4 * g + r;
                        Pw[((row * 128 + (kt * 16 + c) * 2) ^ ((row & 7) << 4)) >> 1] = ph;
                    }
                }
            } else {
                #pragma unroll
                for (int mt = 0; mt < 2; mt++)
                    #pragma unroll
                    for (int r = 0; r < 4; r++) {
                        const int row = mt * 16 + 4 * g + r;
                        Pw[((row * 128 + (kt * 16 + c) * 2) ^ ((row & 7) << 4)) >> 1] = 0;
                    }
            }
        }
        short8 pf[2][2];
        #pragma unroll
        for (int mt = 0; mt < 2; mt++)
            #pragma unroll
            for (int kc = 0; kc < 2; kc++) {
                const int row = mt * 16 + c;
                const int off = (row * 128 + 16 * g + 64 * kc) ^ ((row & 7) << 4);
                pf[mt][kc] = *(const short8*)((const char*)Pw + off);
            }
        #pragma unroll
        for (int dt = 0; dt < 8; dt++) {
            #pragma unroll
            for (int kc = 0; kc < 2; kc++) {
                const short8 vf = *(const short8*)&Vb[(size_t)(dt * 16 + c) * SEQ + k0 + kc * 32 + 8 * g];
                #pragma unroll
                for (int mt = 0; mt < 2; mt++)
                    acc[mt][dt] = __builtin_amdgcn_mfma_f32_16x16x32_bf16(pf[mt][kc], vf, acc[mt][dt], 0, 0, 0);
            }
        }
    }

    // merge partial O into LDS (ds_add_f32)
    #pragma unroll
    for (int mt = 0; mt < 2; mt++)
        #pragma unroll
        for (int dt = 0; dt < 8; dt++)
            #pragma unroll
            for (int r = 0; r < 4; r++)
                atomicAdd(&Obuf[mt * 16 + 4 * g + r][dt * 16 + c], acc[mt][dt][r]);

    // row sums: reduce over c lanes, then LDS add
    #pragma unroll
    for (int mt = 0; mt < 2; mt++)
        #pragma unroll
        for (int r = 0; r < 4; r++) {
            float v = rsum[mt][r];
            v += __shfl_xor(v, 1); v += __shfl_xor(v, 2);
            v += __shfl_xor(v, 4); v += __shfl_xor(v, 8);
            rsum[mt][r] = v;
        }
    if (c == 0) {
        #pragma unroll
        for (int mt = 0; mt < 2; mt++)
            #pragma unroll
            for (int r = 0; r < 4; r++)
                atomicAdd(&Rs[mt * 16 + 4 * g + r], rsum[mt][r]);
    }
    __syncthreads();

    // exclusive streaming writeout
    float* Op = (grav ? OG : OL) + boff + (size_t)q0 * 128;
    #pragma unroll
    for (int i = 0; i < 2; i++) {
        const int v = t + 512 * i;
        const int row = v >> 5, c4 = (v & 31) * 4;
        *(float4*)&Op[row * 128 + c4] = *(const float4*)&Obuf[row][c4];
    }
    if (t < 32) (grav ? GS : LS)[b * SEQ + q0 + t] = Rs[t];
}

// ---------------- finalize: out = 0.7*OL/LS + 0.3*OG/(GS+1e-8) ----------------
__global__ __launch_bounds__(256) void finalize_kernel(
    float* __restrict__ out, const float* __restrict__ OG,
    const float* __restrict__ LS, const float* __restrict__ GS)
{
    const int i4 = blockIdx.x * 256 + threadIdx.x;
    float4 o = ((float4*)out)[i4];
    const float4 gv = ((const float4*)OG)[i4];
    const int row = i4 >> 5;
    const float wl = 0.7f / LS[row];
    const float wg = 0.3f / (GS[row] + 1e-8f);
    o.x = o.x * wl + gv.x * wg;
    o.y = o.y * wl + gv.y * wg;
    o.z = o.z * wl + gv.z * wg;
    o.w = o.w * wl + gv.w * wg;
    ((float4*)out)[i4] = o;
}

extern "C" void kernel_launch(void* const* d_in, const int* in_sizes, int n_in,
                              void* d_out, int out_size, void* d_ws, size_t ws_size,
                              hipStream_t stream) {
    const float* x  = (const float*)d_in[0];
    const float* Wq = (const float*)d_in[1];
    const float* Wk = (const float*)d_in[2];
    const float* Wv = (const float*)d_in[3];
    const float* Lg = (const float*)d_in[4];

    char* ws = (char*)d_ws;
    short* Qh  = (short*)(ws + 0);
    short* Kh  = (short*)(ws + 2097152);
    short* Vh  = (short*)(ws + 4194304);
    short* Yh  = (short*)(ws + 6291456);
    short* Vt  = (short*)(ws + 8388608);
    short* Wt2 = (short*)(ws + 10485760);
    float* SQv = (float*)(ws + 11272192);
    float* LS  = (float*)(ws + 11304960);
    float* GS  = (float*)(ws + 11337728);
    float* OG  = (float*)(ws + 11370496);
    float* OL  = (float*)d_out;

    wt_kernel<<<48, 256, 0, stream>>>(Wq, Wk, Wv, Wt2);
    proj_kernel<<<768, 256, 0, stream>>>(x, Wt2, Qh, Kh, Vh);
    y_kernel<<<512, 256, 0, stream>>>(Kh, Lg, Yh, SQv);
    vt_kernel<<<256, 256, 0, stream>>>(Vh, Vt);
    attn_kernel<<<512, 512, 0, stream>>>(Qh, Kh, Yh, Vt, SQv, OL, OG, LS, GS);
    finalize_kernel<<<1024, 256, 0, stream>>>((float*)d_out, OG, LS, GS);
}

// Round 7
// 171.827 us; speedup vs baseline: 1.3106x; 1.3106x over previous
//
#include <hip/hip_runtime.h>
#include <hip/hip_bf16.h>
#include <math.h>

typedef __attribute__((ext_vector_type(8))) short short8;
typedef __attribute__((ext_vector_type(4))) short s16x4;
typedef __attribute__((ext_vector_type(4))) float f32x4;

#define SEQ 2048
#define DH 128

__device__ __forceinline__ short f2bf(float f) {
    union { float f; unsigned u; } v; v.f = f;
    unsigned r = v.u + 0x7fffu + ((v.u >> 16) & 1u);
    return (short)(r >> 16);
}
__device__ __forceinline__ float bf2f(short s) {
    union { unsigned u; float f; } v; v.u = ((unsigned)(unsigned short)s) << 16;
    return v.f;
}

__device__ __forceinline__ void gll16(const void* g, void* l) {
    __builtin_amdgcn_global_load_lds(
        (const __attribute__((address_space(1))) unsigned int*)g,
        (__attribute__((address_space(3))) unsigned int*)l, 16, 0, 0);
}

// ---------------- Wt2: frag-linear bf16 W ----------------
__global__ __launch_bounds__(256) void wt_kernel(
    const float* __restrict__ Wq, const float* __restrict__ Wk, const float* __restrict__ Wv,
    short* __restrict__ Wt2)
{
    const int t = threadIdx.x;
    const int m  = blockIdx.x >> 4;
    const int ks = blockIdx.x & 15;
    const float* W = m == 0 ? Wq : (m == 1 ? Wk : Wv);
    short* dst = Wt2 + ((size_t)(m * 16 + ks) * 1024) * 8;
    #pragma unroll
    for (int j = 0; j < 4; j++) {
        const int idx = t * 4 + j;
        const int ctile = idx >> 7;
        const int kc = (idx >> 6) & 1;
        const int gg = (idx >> 4) & 3;
        const int cc = idx & 15;
        const int col = ctile * 16 + cc;
        const int kb = ks * 64 + kc * 32 + gg * 8;
        short8 h;
        #pragma unroll
        for (int e = 0; e < 8; e++) h[e] = f2bf(W[(size_t)(kb + e) * 128 + col]);
        *(short8*)&dst[idx * 8] = h;
    }
}

// ---------------- proj: Qh,Kh,Vh (bf16) = x @ W, tiled MFMA ----------------
__global__ __launch_bounds__(256) void proj_kernel(
    const float* __restrict__ x, const short* __restrict__ Wt2,
    short* __restrict__ Qh, short* __restrict__ Kh, short* __restrict__ Vh)
{
    __shared__ short Xs[2048];
    __shared__ short Ws[8192];
    const int t = threadIdx.x;
    const int w = t >> 6, l = t & 63;
    const int c = l & 15, g = l >> 4;
    const int bid = blockIdx.x;
    const int m = bid % 3;
    const int row0 = (bid / 3) * 32;
    const short* Wm = Wt2 + (size_t)m * 16 * 1024 * 8;

    const int xr = t >> 3;
    const int xk = (t & 7) * 8;
    const int xIdx = ((xr >> 4) * 2 + (xk >> 5)) * 64 + ((xk >> 3) & 3) * 16 + (xr & 15);

    const int rt = w & 1;
    const int ct4 = (w >> 1) * 4;
    f32x4 acc[4];
    #pragma unroll
    for (int nt = 0; nt < 4; nt++) acc[nt] = (f32x4)0.f;

    for (int ks = 0; ks < 16; ks++) {
        __syncthreads();
        const short* wsrc = Wm + ((size_t)ks * 1024 + w * 256 + l) * 8;
        #pragma unroll
        for (int j = 0; j < 4; j++)
            gll16(wsrc + j * 64 * 8, (void*)&Ws[(w * 256 + j * 64) * 8]);
        {
            const float* xp = &x[(size_t)(row0 + xr) * 1024 + ks * 64 + xk];
            const float4 a = *(const float4*)xp;
            const float4 b = *(const float4*)(xp + 4);
            short8 h;
            h[0] = f2bf(a.x); h[1] = f2bf(a.y); h[2] = f2bf(a.z); h[3] = f2bf(a.w);
            h[4] = f2bf(b.x); h[5] = f2bf(b.y); h[6] = f2bf(b.z); h[7] = f2bf(b.w);
            *(short8*)&Xs[xIdx * 8] = h;
        }
        __syncthreads();
        #pragma unroll
        for (int kc = 0; kc < 2; kc++) {
            const short8 af = *(const short8*)&Xs[((rt * 2 + kc) * 64 + l) * 8];
            #pragma unroll
            for (int nt = 0; nt < 4; nt++) {
                const short8 bf = *(const short8*)&Ws[(((ct4 + nt) * 2 + kc) * 64 + l) * 8];
                acc[nt] = __builtin_amdgcn_mfma_f32_16x16x32_bf16(af, bf, acc[nt], 0, 0, 0);
            }
        }
    }
    short* Out = m == 0 ? Qh : (m == 1 ? Kh : Vh);
    #pragma unroll
    for (int nt = 0; nt < 4; nt++)
        #pragma unroll
        for (int r = 0; r < 4; r++)
            Out[(size_t)(row0 + rt * 16 + 4 * g + r) * 128 + (ct4 + nt) * 16 + c] = f2bf(acc[nt][r]);
}

// ---------------- y = K @ L (f32 acc), Yh bf16 + SQ from rounded y ----------------
__global__ __launch_bounds__(256) void y_kernel(
    const short* __restrict__ Kh, const float* __restrict__ L,
    short* __restrict__ Yh, float* __restrict__ SQ)
{
    __shared__ float Ls[128 * 128];
    __shared__ short Ks[16][128];
    const int t = threadIdx.x;
    const int row0 = blockIdx.x * 16;
    #pragma unroll
    for (int j = 0; j < 16; j++) {
        int lin = t + j * 256;
        ((float4*)Ls)[lin] = ((const float4*)L)[lin];
    }
    {
        int r = t >> 4, ch = t & 15;
        *(short8*)&Ks[r][ch * 8] = *(const short8*)&Kh[(size_t)(row0 + r) * 128 + ch * 8];
    }
    __syncthreads();
    const int rl = t >> 4, c4 = (t & 15) * 4;
    float acc[8] = {};
    for (int d = 0; d < 128; d++) {
        const float kd = bf2f(Ks[rl][d]);
        const float4 l0 = *(const float4*)&Ls[d * 128 + c4];
        const float4 l1 = *(const float4*)&Ls[d * 128 + c4 + 64];
        acc[0] += kd * l0.x; acc[1] += kd * l0.y; acc[2] += kd * l0.z; acc[3] += kd * l0.w;
        acc[4] += kd * l1.x; acc[5] += kd * l1.y; acc[6] += kd * l1.z; acc[7] += kd * l1.w;
    }
    const int row = row0 + rl;
    s16x4 h0, h1;
    float s = 0.f;
    #pragma unroll
    for (int j = 0; j < 4; j++) {
        short h = f2bf(acc[j]);     float rv = bf2f(h); s += rv * rv; h0[j] = h;
        short g = f2bf(acc[j + 4]); float gv = bf2f(g); s += gv * gv; h1[j] = g;
    }
    *(s16x4*)&Yh[(size_t)row * 128 + c4]      = h0;
    *(s16x4*)&Yh[(size_t)row * 128 + c4 + 64] = h1;
    for (int off = 1; off < 16; off <<= 1) s += __shfl_xor(s, off);
    if ((t & 15) == 0) SQ[row] = s;
}

// ---------------- Vt[b][d 128][key 2048] = Vh[b][key][d] ----------------
__global__ __launch_bounds__(256) void vt_kernel(
    const short* __restrict__ Vh, short* __restrict__ Vt)
{
    __shared__ short Ls[64][72];
    const int t = threadIdx.x;
    const int b  = blockIdx.x >> 6;
    const int nb = (blockIdx.x >> 1) & 31;
    const int db = blockIdx.x & 1;
    const int n0 = nb * 64, d0 = db * 64;
    const short* Vb = Vh + (size_t)b * SEQ * 128;
    short* Vtb = Vt + (size_t)b * 128 * SEQ;
    #pragma unroll
    for (int i = 0; i < 2; i++) {
        int row = (t >> 3) + 32 * i;
        int ch = t & 7;
        *(short8*)&Ls[row][ch * 8] = *(const short8*)&Vb[(size_t)(n0 + row) * 128 + d0 + ch * 8];
    }
    __syncthreads();
    #pragma unroll
    for (int i = 0; i < 2; i++) {
        int dd = (t >> 3) + 32 * i;
        int nc = t & 7;
        short8 v;
        #pragma unroll
        for (int j = 0; j < 8; j++) v[j] = Ls[nc * 8 + j][dd];
        *(short8*)&Vtb[(size_t)(d0 + dd) * SEQ + n0 + nc * 8] = v;
    }
}

// ---------------- fused dual attention, MFMA ----------------
// 256 blocks = grav(2) x b(4) x jp(32); q-pair {jp, 63-jp} -> uniform ~33
// k-tiles/block. 8 waves, stride-8 over key tiles. Per-wave P double-buffered
// (breaks the WAR serialization of the tt loop). Obuf aliases the P region
// (dead after tt loop). No min-waves launch bound: kernel needs ~172 regs,
// any cap below that spills everything (rounds 3/5 lesson).
__global__ __launch_bounds__(512) void attn_kernel(
    const short* __restrict__ Qh, const short* __restrict__ Kh,
    const short* __restrict__ Yh, const short* __restrict__ Vt,
    const float* __restrict__ SQv,
    float* __restrict__ OL, float* __restrict__ OG,
    float* __restrict__ LS, float* __restrict__ GS)
{
    __shared__ __align__(16) short P[8 * 2 * 2048];  // 64 KB: per-wave double-buffered P
    __shared__ float Rs[32];
    float* Obuf = (float*)P;                          // [32][132] alias, used post-loop
    const int t = threadIdx.x;
    const int w = t >> 6, l = t & 63;
    const int c = l & 15, g = l >> 4;
    const int bid = blockIdx.x;
    const int b = bid & 3;
    const int grav = (bid >> 2) & 1;
    const int jp = bid >> 3;

    const size_t boff = (size_t)b * SEQ * 128;
    const short* Ab = (grav ? Yh : Qh) + boff;
    const short* Bb = (grav ? Yh : Kh) + boff;
    const short* Vb = Vt + boff;
    const float* SQb = SQv + b * SEQ;

    // exp(s/sqrt(128)) = 2^(s*0.12751743); exp(-d2/256) = 2^(-d2*0.0056355)
    const float CL = 0.12751743f;
    const float CG = -0.0056355275f;

    for (int m = 0; m < 2; m++) {
        const int qt = m ? 63 - jp : jp;
        const int q0 = qt * 32;
        const int nkt = (qt + 2) >> 1;

        __syncthreads();   // previous phase writeout (Obuf=P region) complete

        short8 qf[2][4];
        #pragma unroll
        for (int mt = 0; mt < 2; mt++)
            #pragma unroll
            for (int kc = 0; kc < 4; kc++)
                qf[mt][kc] = *(const short8*)&Ab[(size_t)(q0 + mt * 16 + c) * 128 + kc * 32 + 8 * g];

        float sqq[2][4];
        if (grav) {
            #pragma unroll
            for (int mt = 0; mt < 2; mt++)
                #pragma unroll
                for (int r = 0; r < 4; r++)
                    sqq[mt][r] = SQb[q0 + mt * 16 + 4 * g + r];
        }

        f32x4 acc[2][8];
        #pragma unroll
        for (int mt = 0; mt < 2; mt++)
            #pragma unroll
            for (int dt = 0; dt < 8; dt++) acc[mt][dt] = (f32x4)0.f;
        float rsum[2][4] = {};

        int pb = 0;
        for (int tt = w; tt < nkt; tt += 8, pb ^= 1) {
            short* Pw = P + (w * 2 + pb) * 2048;
            const int k0 = tt * 64;
            #pragma unroll
            for (int kt = 0; kt < 4; kt++) {
                const int kbase = k0 + kt * 16;
                if (kbase <= q0 + 31) {
                    short8 bf[4];
                    #pragma unroll
                    for (int kc = 0; kc < 4; kc++)
                        bf[kc] = *(const short8*)&Bb[(size_t)(kbase + c) * 128 + kc * 32 + 8 * g];
                    const float sqk = grav ? SQb[kbase + c] : 0.f;
                    #pragma unroll
                    for (int mt = 0; mt < 2; mt++) {
                        f32x4 sc = (f32x4)0.f;
                        #pragma unroll
                        for (int kc = 0; kc < 4; kc++)
                            sc = __builtin_amdgcn_mfma_f32_16x16x32_bf16(qf[mt][kc], bf[kc], sc, 0, 0, 0);
                        #pragma unroll
                        for (int r = 0; r < 4; r++) {
                            const int qrow = q0 + mt * 16 + 4 * g + r;
                            const int key = kbase + c;
                            float p = 0.f;
                            if (key <= qrow) {
                                if (grav) {
                                    float d2 = sqq[mt][r] + sqk - 2.f * sc[r];
                                    d2 = fmaxf(d2, 0.f);
                                    p = __builtin_amdgcn_exp2f(d2 * CG);
                                } else {
                                    p = __builtin_amdgcn_exp2f(sc[r] * CL);
                                }
                            }
                            const short ph = f2bf(p);
                            rsum[mt][r] += bf2f(ph);
                            const int row = mt * 16 + 4 * g + r;
                            Pw[((row * 128 + (kt * 16 + c) * 2) ^ ((row & 7) << 4)) >> 1] = ph;
                        }
                    }
                } else {
                    #pragma unroll
                    for (int mt = 0; mt < 2; mt++)
                        #pragma unroll
                        for (int r = 0; r < 4; r++) {
                            const int row = mt * 16 + 4 * g + r;
                            Pw[((row * 128 + (kt * 16 + c) * 2) ^ ((row & 7) << 4)) >> 1] = 0;
                        }
                }
            }
            short8 pf[2][2];
            #pragma unroll
            for (int mt = 0; mt < 2; mt++)
                #pragma unroll
                for (int kc = 0; kc < 2; kc++) {
                    const int row = mt * 16 + c;
                    const int off = (row * 128 + 16 * g + 64 * kc) ^ ((row & 7) << 4);
                    pf[mt][kc] = *(const short8*)((const char*)Pw + off);
                }
            #pragma unroll
            for (int dt = 0; dt < 8; dt++) {
                #pragma unroll
                for (int kc = 0; kc < 2; kc++) {
                    const short8 vf = *(const short8*)&Vb[(size_t)(dt * 16 + c) * SEQ + k0 + kc * 32 + 8 * g];
                    #pragma unroll
                    for (int mt = 0; mt < 2; mt++)
                        acc[mt][dt] = __builtin_amdgcn_mfma_f32_16x16x32_bf16(pf[mt][kc], vf, acc[mt][dt], 0, 0, 0);
                }
            }
        }

        // ---- all waves' PV done; repurpose P region as Obuf ----
        __syncthreads();
        for (int i = t; i < 32 * 132; i += 512) Obuf[i] = 0.f;
        if (t < 32) Rs[t] = 0.f;
        __syncthreads();

        #pragma unroll
        for (int mt = 0; mt < 2; mt++)
            #pragma unroll
            for (int dt = 0; dt < 8; dt++)
                #pragma unroll
                for (int r = 0; r < 4; r++)
                    atomicAdd(&Obuf[(mt * 16 + 4 * g + r) * 132 + dt * 16 + c], acc[mt][dt][r]);

        #pragma unroll
        for (int mt = 0; mt < 2; mt++)
            #pragma unroll
            for (int r = 0; r < 4; r++) {
                float v = rsum[mt][r];
                v += __shfl_xor(v, 1); v += __shfl_xor(v, 2);
                v += __shfl_xor(v, 4); v += __shfl_xor(v, 8);
                rsum[mt][r] = v;
            }
        if (c == 0) {
            #pragma unroll
            for (int mt = 0; mt < 2; mt++)
                #pragma unroll
                for (int r = 0; r < 4; r++)
                    atomicAdd(&Rs[mt * 16 + 4 * g + r], rsum[mt][r]);
        }
        __syncthreads();

        // exclusive streaming writeout
        float* Op = (grav ? OG : OL) + boff + (size_t)q0 * 128;
        #pragma unroll
        for (int i = 0; i < 2; i++) {
            const int v = t + 512 * i;
            const int row = v >> 5, c4 = (v & 31) * 4;
            *(float4*)&Op[row * 128 + c4] = *(const float4*)&Obuf[row * 132 + c4];
        }
        if (t < 32) (grav ? GS : LS)[b * SEQ + q0 + t] = Rs[t];
    }
}

// ---------------- finalize: out = 0.7*OL/LS + 0.3*OG/(GS+1e-8) ----------------
__global__ __launch_bounds__(256) void finalize_kernel(
    float* __restrict__ out, const float* __restrict__ OG,
    const float* __restrict__ LS, const float* __restrict__ GS)
{
    const int i4 = blockIdx.x * 256 + threadIdx.x;
    float4 o = ((float4*)out)[i4];
    const float4 gv = ((const float4*)OG)[i4];
    const int row = i4 >> 5;
    const float wl = 0.7f / LS[row];
    const float wg = 0.3f / (GS[row] + 1e-8f);
    o.x = o.x * wl + gv.x * wg;
    o.y = o.y * wl + gv.y * wg;
    o.z = o.z * wl + gv.z * wg;
    o.w = o.w * wl + gv.w * wg;
    ((float4*)out)[i4] = o;
}

extern "C" void kernel_launch(void* const* d_in, const int* in_sizes, int n_in,
                              void* d_out, int out_size, void* d_ws, size_t ws_size,
                              hipStream_t stream) {
    const float* x  = (const float*)d_in[0];
    const float* Wq = (const float*)d_in[1];
    const float* Wk = (const float*)d_in[2];
    const float* Wv = (const float*)d_in[3];
    const float* Lg = (const float*)d_in[4];

    char* ws = (char*)d_ws;
    short* Qh  = (short*)(ws + 0);
    short* Kh  = (short*)(ws + 2097152);
    short* Vh  = (short*)(ws + 4194304);
    short* Yh  = (short*)(ws + 6291456);
    short* Vt  = (short*)(ws + 8388608);
    short* Wt2 = (short*)(ws + 10485760);
    float* SQv = (float*)(ws + 11272192);
    float* LS  = (float*)(ws + 11304960);
    float* GS  = (float*)(ws + 11337728);
    float* OG  = (float*)(ws + 11370496);
    float* OL  = (float*)d_out;

    wt_kernel<<<48, 256, 0, stream>>>(Wq, Wk, Wv, Wt2);
    proj_kernel<<<768, 256, 0, stream>>>(x, Wt2, Qh, Kh, Vh);
    y_kernel<<<512, 256, 0, stream>>>(Kh, Lg, Yh, SQv);
    vt_kernel<<<256, 256, 0, stream>>>(Vh, Vt);
    attn_kernel<<<256, 512, 0, stream>>>(Qh, Kh, Yh, Vt, SQv, OL, OG, LS, GS);
    finalize_kernel<<<1024, 256, 0, stream>>>((float*)d_out, OG, LS, GS);
}

// Round 8
// 154.848 us; speedup vs baseline: 1.4543x; 1.1097x over previous
//
#include <hip/hip_runtime.h>
#include <hip/hip_bf16.h>
#include <math.h>

typedef __attribute__((ext_vector_type(8))) short short8;
typedef __attribute__((ext_vector_type(4))) short s16x4;
typedef __attribute__((ext_vector_type(4))) float f32x4;

#define SEQ 2048
#define DH 128

__device__ __forceinline__ short f2bf(float f) {
    union { float f; unsigned u; } v; v.f = f;
    unsigned r = v.u + 0x7fffu + ((v.u >> 16) & 1u);
    return (short)(r >> 16);
}
__device__ __forceinline__ float bf2f(short s) {
    union { unsigned u; float f; } v; v.u = ((unsigned)(unsigned short)s) << 16;
    return v.f;
}

__device__ __forceinline__ void gll16(const void* g, void* l) {
    __builtin_amdgcn_global_load_lds(
        (const __attribute__((address_space(1))) unsigned int*)g,
        (__attribute__((address_space(3))) unsigned int*)l, 16, 0, 0);
}

// ---------------- Wt2: frag-linear bf16 W ----------------
__global__ __launch_bounds__(256) void wt_kernel(
    const float* __restrict__ Wq, const float* __restrict__ Wk, const float* __restrict__ Wv,
    short* __restrict__ Wt2)
{
    const int t = threadIdx.x;
    const int m  = blockIdx.x >> 4;
    const int ks = blockIdx.x & 15;
    const float* W = m == 0 ? Wq : (m == 1 ? Wk : Wv);
    short* dst = Wt2 + ((size_t)(m * 16 + ks) * 1024) * 8;
    #pragma unroll
    for (int j = 0; j < 4; j++) {
        const int idx = t * 4 + j;
        const int ctile = idx >> 7;
        const int kc = (idx >> 6) & 1;
        const int gg = (idx >> 4) & 3;
        const int cc = idx & 15;
        const int col = ctile * 16 + cc;
        const int kb = ks * 64 + kc * 32 + gg * 8;
        short8 h;
        #pragma unroll
        for (int e = 0; e < 8; e++) h[e] = f2bf(W[(size_t)(kb + e) * 128 + col]);
        *(short8*)&dst[idx * 8] = h;
    }
}

// ---------------- proj: Qh,Kh,Vh (bf16) = x @ W, tiled MFMA ----------------
__global__ __launch_bounds__(256) void proj_kernel(
    const float* __restrict__ x, const short* __restrict__ Wt2,
    short* __restrict__ Qh, short* __restrict__ Kh, short* __restrict__ Vh)
{
    __shared__ short Xs[2048];
    __shared__ short Ws[8192];
    const int t = threadIdx.x;
    const int w = t >> 6, l = t & 63;
    const int c = l & 15, g = l >> 4;
    const int bid = blockIdx.x;
    const int m = bid % 3;
    const int row0 = (bid / 3) * 32;
    const short* Wm = Wt2 + (size_t)m * 16 * 1024 * 8;

    const int xr = t >> 3;
    const int xk = (t & 7) * 8;
    const int xIdx = ((xr >> 4) * 2 + (xk >> 5)) * 64 + ((xk >> 3) & 3) * 16 + (xr & 15);

    const int rt = w & 1;
    const int ct4 = (w >> 1) * 4;
    f32x4 acc[4];
    #pragma unroll
    for (int nt = 0; nt < 4; nt++) acc[nt] = (f32x4)0.f;

    for (int ks = 0; ks < 16; ks++) {
        __syncthreads();
        const short* wsrc = Wm + ((size_t)ks * 1024 + w * 256 + l) * 8;
        #pragma unroll
        for (int j = 0; j < 4; j++)
            gll16(wsrc + j * 64 * 8, (void*)&Ws[(w * 256 + j * 64) * 8]);
        {
            const float* xp = &x[(size_t)(row0 + xr) * 1024 + ks * 64 + xk];
            const float4 a = *(const float4*)xp;
            const float4 b = *(const float4*)(xp + 4);
            short8 h;
            h[0] = f2bf(a.x); h[1] = f2bf(a.y); h[2] = f2bf(a.z); h[3] = f2bf(a.w);
            h[4] = f2bf(b.x); h[5] = f2bf(b.y); h[6] = f2bf(b.z); h[7] = f2bf(b.w);
            *(short8*)&Xs[xIdx * 8] = h;
        }
        __syncthreads();
        #pragma unroll
        for (int kc = 0; kc < 2; kc++) {
            const short8 af = *(const short8*)&Xs[((rt * 2 + kc) * 64 + l) * 8];
            #pragma unroll
            for (int nt = 0; nt < 4; nt++) {
                const short8 bf = *(const short8*)&Ws[(((ct4 + nt) * 2 + kc) * 64 + l) * 8];
                acc[nt] = __builtin_amdgcn_mfma_f32_16x16x32_bf16(af, bf, acc[nt], 0, 0, 0);
            }
        }
    }
    short* Out = m == 0 ? Qh : (m == 1 ? Kh : Vh);
    #pragma unroll
    for (int nt = 0; nt < 4; nt++)
        #pragma unroll
        for (int r = 0; r < 4; r++)
            Out[(size_t)(row0 + rt * 16 + 4 * g + r) * 128 + (ct4 + nt) * 16 + c] = f2bf(acc[nt][r]);
}

// ---------------- y = K @ L (f32 acc), Yh bf16 + SQ from rounded y ----------------
__global__ __launch_bounds__(256) void y_kernel(
    const short* __restrict__ Kh, const float* __restrict__ L,
    short* __restrict__ Yh, float* __restrict__ SQ)
{
    __shared__ float Ls[128 * 128];
    __shared__ short Ks[16][128];
    const int t = threadIdx.x;
    const int row0 = blockIdx.x * 16;
    #pragma unroll
    for (int j = 0; j < 16; j++) {
        int lin = t + j * 256;
        ((float4*)Ls)[lin] = ((const float4*)L)[lin];
    }
    {
        int r = t >> 4, ch = t & 15;
        *(short8*)&Ks[r][ch * 8] = *(const short8*)&Kh[(size_t)(row0 + r) * 128 + ch * 8];
    }
    __syncthreads();
    const int rl = t >> 4, c4 = (t & 15) * 4;
    float acc[8] = {};
    for (int d = 0; d < 128; d++) {
        const float kd = bf2f(Ks[rl][d]);
        const float4 l0 = *(const float4*)&Ls[d * 128 + c4];
        const float4 l1 = *(const float4*)&Ls[d * 128 + c4 + 64];
        acc[0] += kd * l0.x; acc[1] += kd * l0.y; acc[2] += kd * l0.z; acc[3] += kd * l0.w;
        acc[4] += kd * l1.x; acc[5] += kd * l1.y; acc[6] += kd * l1.z; acc[7] += kd * l1.w;
    }
    const int row = row0 + rl;
    s16x4 h0, h1;
    float s = 0.f;
    #pragma unroll
    for (int j = 0; j < 4; j++) {
        short h = f2bf(acc[j]);     float rv = bf2f(h); s += rv * rv; h0[j] = h;
        short g = f2bf(acc[j + 4]); float gv = bf2f(g); s += gv * gv; h1[j] = g;
    }
    *(s16x4*)&Yh[(size_t)row * 128 + c4]      = h0;
    *(s16x4*)&Yh[(size_t)row * 128 + c4 + 64] = h1;
    for (int off = 1; off < 16; off <<= 1) s += __shfl_xor(s, off);
    if ((t & 15) == 0) SQ[row] = s;
}

// ---------------- Vt[b][d 128][key 2048] = Vh[b][key][d] ----------------
__global__ __launch_bounds__(256) void vt_kernel(
    const short* __restrict__ Vh, short* __restrict__ Vt)
{
    __shared__ short Ls[64][72];
    const int t = threadIdx.x;
    const int b  = blockIdx.x >> 6;
    const int nb = (blockIdx.x >> 1) & 31;
    const int db = blockIdx.x & 1;
    const int n0 = nb * 64, d0 = db * 64;
    const short* Vb = Vh + (size_t)b * SEQ * 128;
    short* Vtb = Vt + (size_t)b * 128 * SEQ;
    #pragma unroll
    for (int i = 0; i < 2; i++) {
        int row = (t >> 3) + 32 * i;
        int ch = t & 7;
        *(short8*)&Ls[row][ch * 8] = *(const short8*)&Vb[(size_t)(n0 + row) * 128 + d0 + ch * 8];
    }
    __syncthreads();
    #pragma unroll
    for (int i = 0; i < 2; i++) {
        int dd = (t >> 3) + 32 * i;
        int nc = t & 7;
        short8 v;
        #pragma unroll
        for (int j = 0; j < 8; j++) v[j] = Ls[nc * 8 + j][dd];
        *(short8*)&Vtb[(size_t)(d0 + dd) * SEQ + n0 + nc * 8] = v;
    }
}

// ---------------- fused dual attention, MFMA ----------------
// 512 blocks = qt(64, LPT heavy-first) x grav(2) x b(4); 8 waves.
// Wave = (mt = w&1: 16-row q-subtile, ks = w>>1: key-tile class stride 4).
// Per k-tile: B loads in 2 batches interleaved with QK, V loads in 2 batches
// issued ahead of PV -> ~3 exposed latencies/tile (was ~12). All loads
// unconditional (always in-bounds); only exp/P-write is causally masked.
// P: per-wave 16x64 bf16, double-buffered, XOR-swizzled. Merge via LDS adds.
__global__ __launch_bounds__(512) void attn_kernel(
    const short* __restrict__ Qh, const short* __restrict__ Kh,
    const short* __restrict__ Yh, const short* __restrict__ Vt,
    const float* __restrict__ SQv,
    float* __restrict__ OL, float* __restrict__ OG,
    float* __restrict__ LS, float* __restrict__ GS)
{
    __shared__ __align__(16) short P[8 * 2 * 1024];  // 32 KB
    __shared__ float Obuf[32][132];
    __shared__ float Rs[32];
    const int t = threadIdx.x;
    const int w = t >> 6, l = t & 63;
    const int c = l & 15, g = l >> 4;
    const int mt = w & 1, ks = w >> 1;
    const int bid = blockIdx.x;
    const int b = bid & 3;
    const int grav = (bid >> 2) & 1;
    const int qt = 63 - (bid >> 3);
    const int q0 = qt * 32;
    const int nkt = (qt + 2) >> 1;

    for (int i = t; i < 32 * 132; i += 512) ((float*)Obuf)[i] = 0.f;
    if (t < 32) Rs[t] = 0.f;
    __syncthreads();

    const size_t boff = (size_t)b * SEQ * 128;
    const short* Ab = (grav ? Yh : Qh) + boff;
    const short* Bb = (grav ? Yh : Kh) + boff;
    const short* Vb = Vt + boff;
    const float* SQb = SQv + b * SEQ;

    const float CL = 0.12751743f;     // log2(e)/sqrt(128)
    const float CG = -0.0056355275f;  // -log2(e)/256

    short8 qf[4];
    #pragma unroll
    for (int kc = 0; kc < 4; kc++)
        qf[kc] = *(const short8*)&Ab[(size_t)(q0 + mt * 16 + c) * 128 + kc * 32 + 8 * g];

    float sqq[4];
    if (grav) {
        #pragma unroll
        for (int r = 0; r < 4; r++)
            sqq[r] = SQb[q0 + mt * 16 + 4 * g + r];
    }

    f32x4 acc[8];
    #pragma unroll
    for (int dt = 0; dt < 8; dt++) acc[dt] = (f32x4)0.f;
    float rsum[4] = {};

    int pb = 0;
    for (int tt = ks; tt < nkt; tt += 4, pb ^= 1) {
        short* Pw = P + (w * 2 + pb) * 1024;
        const int k0 = tt * 64;

        // ---- batched loads: B kt0-1, V dt0-3, sqk ----
        short8 bfA[2][4];
        #pragma unroll
        for (int kt = 0; kt < 2; kt++)
            #pragma unroll
            for (int kc = 0; kc < 4; kc++)
                bfA[kt][kc] = *(const short8*)&Bb[(size_t)(k0 + kt * 16 + c) * 128 + kc * 32 + 8 * g];
        short8 vfa[4][2];
        #pragma unroll
        for (int dt = 0; dt < 4; dt++)
            #pragma unroll
            for (int kc2 = 0; kc2 < 2; kc2++)
                vfa[dt][kc2] = *(const short8*)&Vb[(size_t)(dt * 16 + c) * SEQ + k0 + kc2 * 32 + 8 * g];
        float sqk[4];
        if (grav) {
            #pragma unroll
            for (int kt = 0; kt < 4; kt++) sqk[kt] = SQb[k0 + kt * 16 + c];
        }
        short8 bfB[2][4];
        #pragma unroll
        for (int kt = 0; kt < 2; kt++)
            #pragma unroll
            for (int kc = 0; kc < 4; kc++)
                bfB[kt][kc] = *(const short8*)&Bb[(size_t)(k0 + (kt + 2) * 16 + c) * 128 + kc * 32 + 8 * g];

        // ---- QK + exp + P-write per kt ----
        #pragma unroll
        for (int kt = 0; kt < 4; kt++) {
            const short8* bk = (kt < 2) ? bfA[kt] : bfB[kt - 2];
            f32x4 sc = (f32x4)0.f;
            #pragma unroll
            for (int kc = 0; kc < 4; kc++)
                sc = __builtin_amdgcn_mfma_f32_16x16x32_bf16(qf[kc], bk[kc], sc, 0, 0, 0);
            const int kbase = k0 + kt * 16;
            const float sqkv = grav ? sqk[kt] : 0.f;
            #pragma unroll
            for (int r = 0; r < 4; r++) {
                const int qrow = q0 + mt * 16 + 4 * g + r;
                const int key = kbase + c;
                float p = 0.f;
                if (key <= qrow) {
                    if (grav) {
                        float d2 = sqq[r] + sqkv - 2.f * sc[r];
                        d2 = fmaxf(d2, 0.f);
                        p = __builtin_amdgcn_exp2f(d2 * CG);
                    } else {
                        p = __builtin_amdgcn_exp2f(sc[r] * CL);
                    }
                }
                const short ph = f2bf(p);
                rsum[r] += bf2f(ph);
                const int row = 4 * g + r;
                Pw[((row * 128 + (kt * 16 + c) * 2) ^ ((row & 7) << 4)) >> 1] = ph;
            }
        }

        // ---- V dt4-7 issue, P read, PV ----
        short8 vfb[4][2];
        #pragma unroll
        for (int dt = 0; dt < 4; dt++)
            #pragma unroll
            for (int kc2 = 0; kc2 < 2; kc2++)
                vfb[dt][kc2] = *(const short8*)&Vb[(size_t)((dt + 4) * 16 + c) * SEQ + k0 + kc2 * 32 + 8 * g];

        short8 pf[2];
        #pragma unroll
        for (int kc2 = 0; kc2 < 2; kc2++) {
            const int off = (c * 128 + 16 * g + 64 * kc2) ^ ((c & 7) << 4);
            pf[kc2] = *(const short8*)((const char*)Pw + off);
        }
        #pragma unroll
        for (int dt = 0; dt < 4; dt++) {
            acc[dt] = __builtin_amdgcn_mfma_f32_16x16x32_bf16(pf[0], vfa[dt][0], acc[dt], 0, 0, 0);
            acc[dt] = __builtin_amdgcn_mfma_f32_16x16x32_bf16(pf[1], vfa[dt][1], acc[dt], 0, 0, 0);
        }
        #pragma unroll
        for (int dt = 0; dt < 4; dt++) {
            acc[dt + 4] = __builtin_amdgcn_mfma_f32_16x16x32_bf16(pf[0], vfb[dt][0], acc[dt + 4], 0, 0, 0);
            acc[dt + 4] = __builtin_amdgcn_mfma_f32_16x16x32_bf16(pf[1], vfb[dt][1], acc[dt + 4], 0, 0, 0);
        }
    }

    // ---- merge partials into LDS ----
    __syncthreads();
    #pragma unroll
    for (int dt = 0; dt < 8; dt++)
        #pragma unroll
        for (int r = 0; r < 4; r++)
            atomicAdd(&Obuf[mt * 16 + 4 * g + r][dt * 16 + c], acc[dt][r]);

    #pragma unroll
    for (int r = 0; r < 4; r++) {
        float v = rsum[r];
        v += __shfl_xor(v, 1); v += __shfl_xor(v, 2);
        v += __shfl_xor(v, 4); v += __shfl_xor(v, 8);
        rsum[r] = v;
    }
    if (c == 0) {
        #pragma unroll
        for (int r = 0; r < 4; r++)
            atomicAdd(&Rs[mt * 16 + 4 * g + r], rsum[r]);
    }
    __syncthreads();

    // ---- exclusive streaming writeout ----
    float* Op = (grav ? OG : OL) + boff + (size_t)q0 * 128;
    #pragma unroll
    for (int i = 0; i < 2; i++) {
        const int v = t + 512 * i;
        const int row = v >> 5, c4 = (v & 31) * 4;
        *(float4*)&Op[row * 128 + c4] = *(const float4*)&Obuf[row][c4];
    }
    if (t < 32) (grav ? GS : LS)[b * SEQ + q0 + t] = Rs[t];
}

// ---------------- finalize: out = 0.7*OL/LS + 0.3*OG/(GS+1e-8) ----------------
__global__ __launch_bounds__(256) void finalize_kernel(
    float* __restrict__ out, const float* __restrict__ OG,
    const float* __restrict__ LS, const float* __restrict__ GS)
{
    const int i4 = blockIdx.x * 256 + threadIdx.x;
    float4 o = ((float4*)out)[i4];
    const float4 gv = ((const float4*)OG)[i4];
    const int row = i4 >> 5;
    const float wl = 0.7f / LS[row];
    const float wg = 0.3f / (GS[row] + 1e-8f);
    o.x = o.x * wl + gv.x * wg;
    o.y = o.y * wl + gv.y * wg;
    o.z = o.z * wl + gv.z * wg;
    o.w = o.w * wl + gv.w * wg;
    ((float4*)out)[i4] = o;
}

extern "C" void kernel_launch(void* const* d_in, const int* in_sizes, int n_in,
                              void* d_out, int out_size, void* d_ws, size_t ws_size,
                              hipStream_t stream) {
    const float* x  = (const float*)d_in[0];
    const float* Wq = (const float*)d_in[1];
    const float* Wk = (const float*)d_in[2];
    const float* Wv = (const float*)d_in[3];
    const float* Lg = (const float*)d_in[4];

    char* ws = (char*)d_ws;
    short* Qh  = (short*)(ws + 0);
    short* Kh  = (short*)(ws + 2097152);
    short* Vh  = (short*)(ws + 4194304);
    short* Yh  = (short*)(ws + 6291456);
    short* Vt  = (short*)(ws + 8388608);
    short* Wt2 = (short*)(ws + 10485760);
    float* SQv = (float*)(ws + 11272192);
    float* LS  = (float*)(ws + 11304960);
    float* GS  = (float*)(ws + 11337728);
    float* OG  = (float*)(ws + 11370496);
    float* OL  = (float*)d_out;

    wt_kernel<<<48, 256, 0, stream>>>(Wq, Wk, Wv, Wt2);
    proj_kernel<<<768, 256, 0, stream>>>(x, Wt2, Qh, Kh, Vh);
    y_kernel<<<512, 256, 0, stream>>>(Kh, Lg, Yh, SQv);
    vt_kernel<<<256, 256, 0, stream>>>(Vh, Vt);
    attn_kernel<<<512, 512, 0, stream>>>(Qh, Kh, Yh, Vt, SQv, OL, OG, LS, GS);
    finalize_kernel<<<1024, 256, 0, stream>>>((float*)d_out, OG, LS, GS);
}

// Round 9
// 140.685 us; speedup vs baseline: 1.6007x; 1.1007x over previous
//
#include <hip/hip_runtime.h>
#include <hip/hip_bf16.h>
#include <math.h>

typedef __attribute__((ext_vector_type(8))) short short8;
typedef __attribute__((ext_vector_type(4))) short s16x4;
typedef __attribute__((ext_vector_type(4))) float f32x4;

#define SEQ 2048
#define DH 128

__device__ __forceinline__ short f2bf(float f) {
    union { float f; unsigned u; } v; v.f = f;
    unsigned r = v.u + 0x7fffu + ((v.u >> 16) & 1u);
    return (short)(r >> 16);
}
__device__ __forceinline__ float bf2f(short s) {
    union { unsigned u; float f; } v; v.u = ((unsigned)(unsigned short)s) << 16;
    return v.f;
}

__device__ __forceinline__ void gll16(const void* g, void* l) {
    __builtin_amdgcn_global_load_lds(
        (const __attribute__((address_space(1))) unsigned int*)g,
        (__attribute__((address_space(3))) unsigned int*)l, 16, 0, 0);
}

// ---------------- Wt2: frag-linear bf16 W ----------------
__global__ __launch_bounds__(256) void wt_kernel(
    const float* __restrict__ Wq, const float* __restrict__ Wk, const float* __restrict__ Wv,
    short* __restrict__ Wt2)
{
    const int t = threadIdx.x;
    const int m  = blockIdx.x >> 4;
    const int ks = blockIdx.x & 15;
    const float* W = m == 0 ? Wq : (m == 1 ? Wk : Wv);
    short* dst = Wt2 + ((size_t)(m * 16 + ks) * 1024) * 8;
    #pragma unroll
    for (int j = 0; j < 4; j++) {
        const int idx = t * 4 + j;
        const int ctile = idx >> 7;
        const int kc = (idx >> 6) & 1;
        const int gg = (idx >> 4) & 3;
        const int cc = idx & 15;
        const int col = ctile * 16 + cc;
        const int kb = ks * 64 + kc * 32 + gg * 8;
        short8 h;
        #pragma unroll
        for (int e = 0; e < 8; e++) h[e] = f2bf(W[(size_t)(kb + e) * 128 + col]);
        *(short8*)&dst[idx * 8] = h;
    }
}

// ---------------- proj: Qh,Kh,Vh (bf16) = x @ W, tiled MFMA ----------------
__global__ __launch_bounds__(256) void proj_kernel(
    const float* __restrict__ x, const short* __restrict__ Wt2,
    short* __restrict__ Qh, short* __restrict__ Kh, short* __restrict__ Vh)
{
    __shared__ short Xs[2048];
    __shared__ short Ws[8192];
    const int t = threadIdx.x;
    const int w = t >> 6, l = t & 63;
    const int c = l & 15, g = l >> 4;
    const int bid = blockIdx.x;
    const int m = bid % 3;
    const int row0 = (bid / 3) * 32;
    const short* Wm = Wt2 + (size_t)m * 16 * 1024 * 8;

    const int xr = t >> 3;
    const int xk = (t & 7) * 8;
    const int xIdx = ((xr >> 4) * 2 + (xk >> 5)) * 64 + ((xk >> 3) & 3) * 16 + (xr & 15);

    const int rt = w & 1;
    const int ct4 = (w >> 1) * 4;
    f32x4 acc[4];
    #pragma unroll
    for (int nt = 0; nt < 4; nt++) acc[nt] = (f32x4)0.f;

    for (int ks = 0; ks < 16; ks++) {
        __syncthreads();
        const short* wsrc = Wm + ((size_t)ks * 1024 + w * 256 + l) * 8;
        #pragma unroll
        for (int j = 0; j < 4; j++)
            gll16(wsrc + j * 64 * 8, (void*)&Ws[(w * 256 + j * 64) * 8]);
        {
            const float* xp = &x[(size_t)(row0 + xr) * 1024 + ks * 64 + xk];
            const float4 a = *(const float4*)xp;
            const float4 b = *(const float4*)(xp + 4);
            short8 h;
            h[0] = f2bf(a.x); h[1] = f2bf(a.y); h[2] = f2bf(a.z); h[3] = f2bf(a.w);
            h[4] = f2bf(b.x); h[5] = f2bf(b.y); h[6] = f2bf(b.z); h[7] = f2bf(b.w);
            *(short8*)&Xs[xIdx * 8] = h;
        }
        __syncthreads();
        #pragma unroll
        for (int kc = 0; kc < 2; kc++) {
            const short8 af = *(const short8*)&Xs[((rt * 2 + kc) * 64 + l) * 8];
            #pragma unroll
            for (int nt = 0; nt < 4; nt++) {
                const short8 bf = *(const short8*)&Ws[(((ct4 + nt) * 2 + kc) * 64 + l) * 8];
                acc[nt] = __builtin_amdgcn_mfma_f32_16x16x32_bf16(af, bf, acc[nt], 0, 0, 0);
            }
        }
    }
    short* Out = m == 0 ? Qh : (m == 1 ? Kh : Vh);
    #pragma unroll
    for (int nt = 0; nt < 4; nt++)
        #pragma unroll
        for (int r = 0; r < 4; r++)
            Out[(size_t)(row0 + rt * 16 + 4 * g + r) * 128 + (ct4 + nt) * 16 + c] = f2bf(acc[nt][r]);
}

// ---------------- y = K @ L (f32 acc), Yh bf16 + SQ from rounded y ----------------
__global__ __launch_bounds__(256) void y_kernel(
    const short* __restrict__ Kh, const float* __restrict__ L,
    short* __restrict__ Yh, float* __restrict__ SQ)
{
    __shared__ float Ls[128 * 128];
    __shared__ short Ks[16][128];
    const int t = threadIdx.x;
    const int row0 = blockIdx.x * 16;
    #pragma unroll
    for (int j = 0; j < 16; j++) {
        int lin = t + j * 256;
        ((float4*)Ls)[lin] = ((const float4*)L)[lin];
    }
    {
        int r = t >> 4, ch = t & 15;
        *(short8*)&Ks[r][ch * 8] = *(const short8*)&Kh[(size_t)(row0 + r) * 128 + ch * 8];
    }
    __syncthreads();
    const int rl = t >> 4, c4 = (t & 15) * 4;
    float acc[8] = {};
    for (int d = 0; d < 128; d++) {
        const float kd = bf2f(Ks[rl][d]);
        const float4 l0 = *(const float4*)&Ls[d * 128 + c4];
        const float4 l1 = *(const float4*)&Ls[d * 128 + c4 + 64];
        acc[0] += kd * l0.x; acc[1] += kd * l0.y; acc[2] += kd * l0.z; acc[3] += kd * l0.w;
        acc[4] += kd * l1.x; acc[5] += kd * l1.y; acc[6] += kd * l1.z; acc[7] += kd * l1.w;
    }
    const int row = row0 + rl;
    s16x4 h0, h1;
    float s = 0.f;
    #pragma unroll
    for (int j = 0; j < 4; j++) {
        short h = f2bf(acc[j]);     float rv = bf2f(h); s += rv * rv; h0[j] = h;
        short g = f2bf(acc[j + 4]); float gv = bf2f(g); s += gv * gv; h1[j] = g;
    }
    *(s16x4*)&Yh[(size_t)row * 128 + c4]      = h0;
    *(s16x4*)&Yh[(size_t)row * 128 + c4 + 64] = h1;
    for (int off = 1; off < 16; off <<= 1) s += __shfl_xor(s, off);
    if ((t & 15) == 0) SQ[row] = s;
}

// ---------------- Vt[b][d 128][key 2048] = Vh[b][key][d] ----------------
__global__ __launch_bounds__(256) void vt_kernel(
    const short* __restrict__ Vh, short* __restrict__ Vt)
{
    __shared__ short Ls[64][72];
    const int t = threadIdx.x;
    const int b  = blockIdx.x >> 6;
    const int nb = (blockIdx.x >> 1) & 31;
    const int db = blockIdx.x & 1;
    const int n0 = nb * 64, d0 = db * 64;
    const short* Vb = Vh + (size_t)b * SEQ * 128;
    short* Vtb = Vt + (size_t)b * 128 * SEQ;
    #pragma unroll
    for (int i = 0; i < 2; i++) {
        int row = (t >> 3) + 32 * i;
        int ch = t & 7;
        *(short8*)&Ls[row][ch * 8] = *(const short8*)&Vb[(size_t)(n0 + row) * 128 + d0 + ch * 8];
    }
    __syncthreads();
    #pragma unroll
    for (int i = 0; i < 2; i++) {
        int dd = (t >> 3) + 32 * i;
        int nc = t & 7;
        short8 v;
        #pragma unroll
        for (int j = 0; j < 8; j++) v[j] = Ls[nc * 8 + j][dd];
        *(short8*)&Vtb[(size_t)(d0 + dd) * SEQ + n0 + nc * 8] = v;
    }
}

// ---------------- fused dual attention: LDS-staged, double-buffered ----------------
// 512 blocks = qt(64, LPT) x grav(2) x b(4), 4 waves (256 thr).
// Block owns 32 q-rows. Per 64-key tile: B-tile(16KB) + V-tile(16KB) staged
// frag-linear via global_load_lds (per-lane SOURCE permutation, LDS linear),
// double-buffered; one __syncthreads per tile (its vmcnt drain = staging fence).
// Wave = (qh = w&1: 16 q-rows, kh = w>>1: 32-key half). P per-wave 1KB x2 LDS.
__global__ __launch_bounds__(256, 2) void attn_kernel(
    const short* __restrict__ Qh, const short* __restrict__ Kh,
    const short* __restrict__ Yh, const short* __restrict__ Vt,
    const float* __restrict__ SQv,
    float* __restrict__ OL, float* __restrict__ OG,
    float* __restrict__ LS, float* __restrict__ GS)
{
    __shared__ __align__(16) short Bs[2][8192];   // 32 KB: B tile, frag-linear
    __shared__ __align__(16) short Vs[2][8192];   // 32 KB: V tile, frag-linear
    __shared__ __align__(16) short P[4 * 2 * 512];// 8 KB: per-wave dbuf P (16x32)
    __shared__ float Rs[32];
    float* Obuf = (float*)&Bs[0][0];              // [32][132] alias, post-loop only

    const int t = threadIdx.x;
    const int w = t >> 6, l = t & 63;
    const int c = l & 15, g = l >> 4;
    const int qh = w & 1, kh = w >> 1;
    const int wbase = t & 192;                    // w*64
    const int bid = blockIdx.x;
    const int b = bid & 3;
    const int grav = (bid >> 2) & 1;
    const int qt = 63 - (bid >> 3);               // LPT: heavy first, self-balancing
    const int q0 = qt * 32;
    const int nkt = (qt + 2) >> 1;

    const size_t boff = (size_t)b * SEQ * 128;
    const short* Ab = (grav ? Yh : Qh) + boff;
    const short* Bb = (grav ? Yh : Kh) + boff;
    const short* Vb = Vt + boff;                  // [128][2048]
    const float* SQb = SQv + b * SEQ;

    const float CL = 0.12751743f;                 // log2(e)/sqrt(128)
    const float CG = -0.0056355275f;              // -log2(e)/256

    // per-thread staging source bases (frag-linear unit u = j*256 + t)
    const short* bsrc[4];
    const short* vsrc[4];
    #pragma unroll
    for (int j = 0; j < 4; j++) {
        const int u = j * 256 + t;
        bsrc[j] = Bb + (size_t)(u & 63) * 128 + (u >> 6) * 8;
        vsrc[j] = Vb + (size_t)(u & 127) * SEQ + (u >> 7) * 8;
    }

    // Q-side fragments + sqq
    short8 qf[4];
    #pragma unroll
    for (int kc = 0; kc < 4; kc++)
        qf[kc] = *(const short8*)&Ab[(size_t)(q0 + qh * 16 + c) * 128 + kc * 32 + 8 * g];
    float sqq[4];
    if (grav) {
        #pragma unroll
        for (int r = 0; r < 4; r++)
            sqq[r] = SQb[q0 + qh * 16 + 4 * g + r];
    }

    f32x4 acc[8];
    #pragma unroll
    for (int dt = 0; dt < 8; dt++) acc[dt] = (f32x4)0.f;
    float rsum[4] = {};

    // prologue: stage tile 0 into buffer 0
    #pragma unroll
    for (int j = 0; j < 4; j++) gll16(bsrc[j], (void*)&Bs[0][(j * 256 + wbase) * 8]);
    #pragma unroll
    for (int j = 0; j < 4; j++) gll16(vsrc[j], (void*)&Vs[0][(j * 256 + wbase) * 8]);

    int cur = 0, pb = 0;
    for (int ti = 0; ti < nkt; ti++, cur ^= 1, pb ^= 1) {
        const int k0 = ti * 64;
        __syncthreads();   // drains vmcnt: buf[cur] staged; prior reads of buf[cur^1] done
        if (ti + 1 < nkt) {
            const int kn = k0 + 64;
            #pragma unroll
            for (int j = 0; j < 4; j++)
                gll16(bsrc[j] + (size_t)kn * 128, (void*)&Bs[cur ^ 1][(j * 256 + wbase) * 8]);
            #pragma unroll
            for (int j = 0; j < 4; j++)
                gll16(vsrc[j] + kn, (void*)&Vs[cur ^ 1][(j * 256 + wbase) * 8]);
        }

        short* Pp = P + (w * 2 + pb) * 512;

        // ---- QK^T + exp + P-write (keys: kh*32 + kt*16 + c) ----
        #pragma unroll
        for (int kt = 0; kt < 2; kt++) {
            f32x4 sc = (f32x4)0.f;
            #pragma unroll
            for (int kc = 0; kc < 4; kc++) {
                const short8 bf = *(const short8*)
                    &Bs[cur][((kc * 4 + g) * 64 + kh * 32 + kt * 16 + c) * 8];
                sc = __builtin_amdgcn_mfma_f32_16x16x32_bf16(qf[kc], bf, sc, 0, 0, 0);
            }
            const int key = k0 + kh * 32 + kt * 16 + c;
            const float sqkv = grav ? SQb[key] : 0.f;
            #pragma unroll
            for (int r = 0; r < 4; r++) {
                const int qrow = q0 + qh * 16 + 4 * g + r;
                float p = 0.f;
                if (key <= qrow) {
                    if (grav) {
                        float d2 = sqq[r] + sqkv - 2.f * sc[r];
                        d2 = fmaxf(d2, 0.f);
                        p = __builtin_amdgcn_exp2f(d2 * CG);
                    } else {
                        p = __builtin_amdgcn_exp2f(sc[r] * CL);
                    }
                }
                const short ph = f2bf(p);
                rsum[r] += bf2f(ph);
                const int row = 4 * g + r;
                Pp[row * 32 + ((kt * 16 + c) ^ (g << 3))] = ph;  // swz = (row>>2)&3 = g
            }
        }

        // ---- PV: A = P row c (K=32, its key half), B = staged V ----
        const short8 pf = *(const short8*)&Pp[c * 32 + 8 * (g ^ ((c >> 2) & 3))];
        #pragma unroll
        for (int dt = 0; dt < 8; dt++) {
            const short8 vf = *(const short8*)
                &Vs[cur][((kh * 4 + g) * 128 + dt * 16 + c) * 8];
            acc[dt] = __builtin_amdgcn_mfma_f32_16x16x32_bf16(pf, vf, acc[dt], 0, 0, 0);
        }
    }

    // ---- merge across waves via LDS (Obuf aliases Bs, dead now) ----
    __syncthreads();
    for (int i = t; i < 32 * 132; i += 256) Obuf[i] = 0.f;
    if (t < 32) Rs[t] = 0.f;
    __syncthreads();

    #pragma unroll
    for (int dt = 0; dt < 8; dt++)
        #pragma unroll
        for (int r = 0; r < 4; r++)
            atomicAdd(&Obuf[(qh * 16 + 4 * g + r) * 132 + dt * 16 + c], acc[dt][r]);

    #pragma unroll
    for (int r = 0; r < 4; r++) {
        float v = rsum[r];
        v += __shfl_xor(v, 1); v += __shfl_xor(v, 2);
        v += __shfl_xor(v, 4); v += __shfl_xor(v, 8);
        rsum[r] = v;
    }
    if (c == 0) {
        #pragma unroll
        for (int r = 0; r < 4; r++)
            atomicAdd(&Rs[qh * 16 + 4 * g + r], rsum[r]);
    }
    __syncthreads();

    float* Op = (grav ? OG : OL) + boff + (size_t)q0 * 128;
    #pragma unroll
    for (int i = 0; i < 4; i++) {
        const int v = t + 256 * i;
        const int row = v >> 5, c4 = (v & 31) * 4;
        *(float4*)&Op[row * 128 + c4] = *(const float4*)&Obuf[row * 132 + c4];
    }
    if (t < 32) (grav ? GS : LS)[b * SEQ + q0 + t] = Rs[t];
}

// ---------------- finalize: out = 0.7*OL/LS + 0.3*OG/(GS+1e-8) ----------------
__global__ __launch_bounds__(256) void finalize_kernel(
    float* __restrict__ out, const float* __restrict__ OG,
    const float* __restrict__ LS, const float* __restrict__ GS)
{
    const int i4 = blockIdx.x * 256 + threadIdx.x;
    float4 o = ((float4*)out)[i4];
    const float4 gv = ((const float4*)OG)[i4];
    const int row = i4 >> 5;
    const float wl = 0.7f / LS[row];
    const float wg = 0.3f / (GS[row] + 1e-8f);
    o.x = o.x * wl + gv.x * wg;
    o.y = o.y * wl + gv.y * wg;
    o.z = o.z * wl + gv.z * wg;
    o.w = o.w * wl + gv.w * wg;
    ((float4*)out)[i4] = o;
}

extern "C" void kernel_launch(void* const* d_in, const int* in_sizes, int n_in,
                              void* d_out, int out_size, void* d_ws, size_t ws_size,
                              hipStream_t stream) {
    const float* x  = (const float*)d_in[0];
    const float* Wq = (const float*)d_in[1];
    const float* Wk = (const float*)d_in[2];
    const float* Wv = (const float*)d_in[3];
    const float* Lg = (const float*)d_in[4];

    char* ws = (char*)d_ws;
    short* Qh  = (short*)(ws + 0);
    short* Kh  = (short*)(ws + 2097152);
    short* Vh  = (short*)(ws + 4194304);
    short* Yh  = (short*)(ws + 6291456);
    short* Vt  = (short*)(ws + 8388608);
    short* Wt2 = (short*)(ws + 10485760);
    float* SQv = (float*)(ws + 11272192);
    float* LS  = (float*)(ws + 11304960);
    float* GS  = (float*)(ws + 11337728);
    float* OG  = (float*)(ws + 11370496);
    float* OL  = (float*)d_out;

    wt_kernel<<<48, 256, 0, stream>>>(Wq, Wk, Wv, Wt2);
    proj_kernel<<<768, 256, 0, stream>>>(x, Wt2, Qh, Kh, Vh);
    y_kernel<<<512, 256, 0, stream>>>(Kh, Lg, Yh, SQv);
    vt_kernel<<<256, 256, 0, stream>>>(Vh, Vt);
    attn_kernel<<<512, 256, 0, stream>>>(Qh, Kh, Yh, Vt, SQv, OL, OG, LS, GS);
    finalize_kernel<<<1024, 256, 0, stream>>>((float*)d_out, OG, LS, GS);
}

// Round 10
// 127.883 us; speedup vs baseline: 1.7609x; 1.1001x over previous
//
#include <hip/hip_runtime.h>
#include <hip/hip_bf16.h>
#include <math.h>

typedef __attribute__((ext_vector_type(8))) short short8;
typedef __attribute__((ext_vector_type(4))) short s16x4;
typedef __attribute__((ext_vector_type(4))) float f32x4;

#define SEQ 2048
#define DH 128

// frag-linear layout for [8192][128] bf16 matrices, 64-row tiles:
//   element (R, col) -> (R>>6)*8192 + ((col>>3)*64 + (R&63))*8 + (col&7)
// V frag (transposed) per 64-key tile:
//   element (key, d) -> (key>>6)*8192 + (((key&63)>>3)*128 + d)*8 + (key&7)

__device__ __forceinline__ short f2bf(float f) {
    union { float f; unsigned u; } v; v.f = f;
    unsigned r = v.u + 0x7fffu + ((v.u >> 16) & 1u);
    return (short)(r >> 16);
}
__device__ __forceinline__ float bf2f(short s) {
    union { unsigned u; float f; } v; v.u = ((unsigned)(unsigned short)s) << 16;
    return v.f;
}

__device__ __forceinline__ void gll16(const void* g, void* l) {
    __builtin_amdgcn_global_load_lds(
        (const __attribute__((address_space(1))) unsigned int*)g,
        (__attribute__((address_space(3))) unsigned int*)l, 16, 0, 0);
}

// ---------------- Wt2: frag-linear bf16 W (for proj staging) ----------------
__global__ __launch_bounds__(256) void wt_kernel(
    const float* __restrict__ Wq, const float* __restrict__ Wk, const float* __restrict__ Wv,
    short* __restrict__ Wt2)
{
    const int t = threadIdx.x;
    const int m  = blockIdx.x >> 4;
    const int ks = blockIdx.x & 15;
    const float* W = m == 0 ? Wq : (m == 1 ? Wk : Wv);
    short* dst = Wt2 + ((size_t)(m * 16 + ks) * 1024) * 8;
    #pragma unroll
    for (int j = 0; j < 4; j++) {
        const int idx = t * 4 + j;
        const int ctile = idx >> 7;
        const int kc = (idx >> 6) & 1;
        const int gg = (idx >> 4) & 3;
        const int cc = idx & 15;
        const int col = ctile * 16 + cc;
        const int kb = ks * 64 + kc * 32 + gg * 8;
        short8 h;
        #pragma unroll
        for (int e = 0; e < 8; e++) h[e] = f2bf(W[(size_t)(kb + e) * 128 + col]);
        *(short8*)&dst[idx * 8] = h;
    }
}

// ---------------- proj: Qh,Kh (frag-linear) and Vh (row-major) = x @ W ----------------
__global__ __launch_bounds__(256) void proj_kernel(
    const float* __restrict__ x, const short* __restrict__ Wt2,
    short* __restrict__ Qh, short* __restrict__ Kh, short* __restrict__ Vh)
{
    __shared__ short Xs[2048];
    __shared__ short Ws[8192];
    const int t = threadIdx.x;
    const int w = t >> 6, l = t & 63;
    const int c = l & 15, g = l >> 4;
    const int bid = blockIdx.x;
    const int m = bid % 3;
    const int row0 = (bid / 3) * 32;
    const short* Wm = Wt2 + (size_t)m * 16 * 1024 * 8;

    const int xr = t >> 3;
    const int xk = (t & 7) * 8;
    const int xIdx = ((xr >> 4) * 2 + (xk >> 5)) * 64 + ((xk >> 3) & 3) * 16 + (xr & 15);

    const int rt = w & 1;
    const int ct4 = (w >> 1) * 4;
    f32x4 acc[4];
    #pragma unroll
    for (int nt = 0; nt < 4; nt++) acc[nt] = (f32x4)0.f;

    for (int ks = 0; ks < 16; ks++) {
        __syncthreads();
        const short* wsrc = Wm + ((size_t)ks * 1024 + w * 256 + l) * 8;
        #pragma unroll
        for (int j = 0; j < 4; j++)
            gll16(wsrc + j * 64 * 8, (void*)&Ws[(w * 256 + j * 64) * 8]);
        {
            const float* xp = &x[(size_t)(row0 + xr) * 1024 + ks * 64 + xk];
            const float4 a = *(const float4*)xp;
            const float4 b = *(const float4*)(xp + 4);
            short8 h;
            h[0] = f2bf(a.x); h[1] = f2bf(a.y); h[2] = f2bf(a.z); h[3] = f2bf(a.w);
            h[4] = f2bf(b.x); h[5] = f2bf(b.y); h[6] = f2bf(b.z); h[7] = f2bf(b.w);
            *(short8*)&Xs[xIdx * 8] = h;
        }
        __syncthreads();
        #pragma unroll
        for (int kc = 0; kc < 2; kc++) {
            const short8 af = *(const short8*)&Xs[((rt * 2 + kc) * 64 + l) * 8];
            #pragma unroll
            for (int nt = 0; nt < 4; nt++) {
                const short8 bf = *(const short8*)&Ws[(((ct4 + nt) * 2 + kc) * 64 + l) * 8];
                acc[nt] = __builtin_amdgcn_mfma_f32_16x16x32_bf16(af, bf, acc[nt], 0, 0, 0);
            }
        }
    }
    short* Out = m == 0 ? Qh : (m == 1 ? Kh : Vh);
    #pragma unroll
    for (int nt = 0; nt < 4; nt++)
        #pragma unroll
        for (int r = 0; r < 4; r++) {
            const int R = row0 + rt * 16 + 4 * g + r;
            const int col = (ct4 + nt) * 16 + c;
            const short hv = f2bf(acc[nt][r]);
            if (m == 2)
                Out[(size_t)R * 128 + col] = hv;                              // V row-major
            else
                Out[(size_t)(R >> 6) * 8192 + ((col >> 3) * 64 + (R & 63)) * 8 + (col & 7)] = hv;
        }
}

// ---------------- y = K @ L (f32 acc): Yh frag-linear + SQ from rounded y ----------------
__global__ __launch_bounds__(256) void y_kernel(
    const short* __restrict__ Kh, const float* __restrict__ L,
    short* __restrict__ Yh, float* __restrict__ SQ)
{
    __shared__ float Ls[128 * 128];
    __shared__ short Ks[16][128];
    const int t = threadIdx.x;
    const int row0 = blockIdx.x * 16;
    #pragma unroll
    for (int j = 0; j < 16; j++) {
        int lin = t + j * 256;
        ((float4*)Ls)[lin] = ((const float4*)L)[lin];
    }
    {
        int r = t >> 4, ch = t & 15;
        const int R = row0 + r;
        *(short8*)&Ks[r][ch * 8] =
            *(const short8*)&Kh[(size_t)(R >> 6) * 8192 + (ch * 64 + (R & 63)) * 8];
    }
    __syncthreads();
    const int rl = t >> 4, c4 = (t & 15) * 4;
    float acc[8] = {};
    for (int d = 0; d < 128; d++) {
        const float kd = bf2f(Ks[rl][d]);
        const float4 l0 = *(const float4*)&Ls[d * 128 + c4];
        const float4 l1 = *(const float4*)&Ls[d * 128 + c4 + 64];
        acc[0] += kd * l0.x; acc[1] += kd * l0.y; acc[2] += kd * l0.z; acc[3] += kd * l0.w;
        acc[4] += kd * l1.x; acc[5] += kd * l1.y; acc[6] += kd * l1.z; acc[7] += kd * l1.w;
    }
    const int R = row0 + rl;
    s16x4 h0, h1;
    float s = 0.f;
    #pragma unroll
    for (int j = 0; j < 4; j++) {
        short h = f2bf(acc[j]);     float rv = bf2f(h); s += rv * rv; h0[j] = h;
        short g = f2bf(acc[j + 4]); float gv = bf2f(g); s += gv * gv; h1[j] = g;
    }
    const size_t base = (size_t)(R >> 6) * 8192 + (size_t)(R & 63) * 8;
    *(s16x4*)&Yh[base + (c4 >> 3) * 512 + (c4 & 7)] = h0;
    *(s16x4*)&Yh[base + ((c4 + 64) >> 3) * 512 + (c4 & 7)] = h1;
    for (int off = 1; off < 16; off <<= 1) s += __shfl_xor(s, off);
    if ((t & 15) == 0) SQ[R] = s;
}

// ---------------- Vf: V in transposed frag-linear tiles ----------------
__global__ __launch_bounds__(256) void vt_kernel(
    const short* __restrict__ Vh, short* __restrict__ Vf)
{
    __shared__ short Ls[64][72];
    const int t = threadIdx.x;
    const int b  = blockIdx.x >> 6;
    const int nb = (blockIdx.x >> 1) & 31;
    const int db = blockIdx.x & 1;
    const int n0 = nb * 64, d0 = db * 64;
    const short* Vb = Vh + (size_t)b * SEQ * 128;
    short* Vfb = Vf + (size_t)b * SEQ * 128;
    #pragma unroll
    for (int i = 0; i < 2; i++) {
        int row = (t >> 3) + 32 * i;
        int ch = t & 7;
        *(short8*)&Ls[row][ch * 8] = *(const short8*)&Vb[(size_t)(n0 + row) * 128 + d0 + ch * 8];
    }
    __syncthreads();
    #pragma unroll
    for (int i = 0; i < 2; i++) {
        int dd = (t >> 3) + 32 * i;
        int nc = t & 7;
        short8 v;
        #pragma unroll
        for (int j = 0; j < 8; j++) v[j] = Ls[nc * 8 + j][dd];
        *(short8*)&Vfb[(size_t)(n0 >> 6) * 8192 + (nc * 128 + d0 + dd) * 8] = v;
    }
}

// ---------------- fused dual attention: coalesced LDS staging, uniform blocks ----------------
// 512 blocks = jp(32) x s(2) x grav(2) x b(4); block does q-pair {jp,63-jp},
// key tiles tt ≡ s (mod 2) -> ~17 tiles/block, uniform. 4 waves.
// B/V tiles staged via global_load_lds from PRE-FRAGGED global (fully
// coalesced 1KB/instr), double-buffered. 2-way cross-block merge via global
// atomics (deterministic: fp add commutative, 2 contributors).
__global__ __launch_bounds__(256, 2) void attn_kernel(
    const short* __restrict__ Qf, const short* __restrict__ Kf,
    const short* __restrict__ Yf, const short* __restrict__ Vf,
    const float* __restrict__ SQv,
    float* __restrict__ OL, float* __restrict__ OG,
    float* __restrict__ LS, float* __restrict__ GS)
{
    __shared__ __align__(16) short Bs[2][8192];    // 32 KB
    __shared__ __align__(16) short Vs[2][8192];    // 32 KB
    __shared__ __align__(16) short P[4 * 2 * 512]; // 8 KB per-wave dbuf P
    __shared__ float Rs[32];
    float* Obuf = (float*)&Bs[0][0];               // [32][132] alias, post-loop only

    const int t = threadIdx.x;
    const int w = t >> 6, l = t & 63;
    const int c = l & 15, g = l >> 4;
    const int qh = w & 1, kh = w >> 1;
    const int wbase = t & 192;                     // w*64
    const int bid = blockIdx.x;
    const int b = bid & 3;
    const int grav = (bid >> 2) & 1;
    const int s = (bid >> 3) & 1;
    const int jp = bid >> 4;

    const size_t fb = (size_t)b * SEQ * 128;
    const short* Ap = (grav ? Yf : Qf) + fb;
    const short* Bp = (grav ? Yf : Kf) + fb;
    const short* Vp = Vf + fb;
    const float* SQb = SQv + b * SEQ;

    const float CL = 0.12751743f;                  // log2(e)/sqrt(128)
    const float CG = -0.0056355275f;               // -log2(e)/256

    for (int m = 0; m < 2; m++) {
        const int qt = m ? 63 - jp : jp;
        const int q0 = qt * 32;
        const int nkt = (qt + 2) >> 1;

        __syncthreads();   // previous epilogue's Obuf (aliasing Bs) reads done

        short8 qf[4];
        const size_t qtb = (size_t)(qt >> 1) * 8192;
        const int qlocal = (qt & 1) * 32 + qh * 16 + c;
        #pragma unroll
        for (int kc = 0; kc < 4; kc++)
            qf[kc] = *(const short8*)&Ap[qtb + ((kc * 4 + g) * 64 + qlocal) * 8];

        float sqq[4];
        if (grav) {
            #pragma unroll
            for (int r = 0; r < 4; r++)
                sqq[r] = SQb[q0 + qh * 16 + 4 * g + r];
        }

        f32x4 acc[8];
        #pragma unroll
        for (int dt = 0; dt < 8; dt++) acc[dt] = (f32x4)0.f;
        float rsum[4] = {};

        if (s < nkt) {
            {   // prologue: stage tile s into buffer 0 (coalesced)
                const short* bs0 = Bp + (size_t)s * 8192;
                const short* vs0 = Vp + (size_t)s * 8192;
                #pragma unroll
                for (int j = 0; j < 4; j++)
                    gll16(bs0 + (j * 256 + t) * 8, (void*)&Bs[0][(j * 256 + wbase) * 8]);
                #pragma unroll
                for (int j = 0; j < 4; j++)
                    gll16(vs0 + (j * 256 + t) * 8, (void*)&Vs[0][(j * 256 + wbase) * 8]);
            }
            int cur = 0, pb = 0;
            for (int tt = s; tt < nkt; tt += 2, cur ^= 1, pb ^= 1) {
                __syncthreads();   // buf[cur] staged; prior reads of buf[cur^1] done
                if (tt + 2 < nkt) {
                    const short* bsn = Bp + (size_t)(tt + 2) * 8192;
                    const short* vsn = Vp + (size_t)(tt + 2) * 8192;
                    #pragma unroll
                    for (int j = 0; j < 4; j++)
                        gll16(bsn + (j * 256 + t) * 8, (void*)&Bs[cur ^ 1][(j * 256 + wbase) * 8]);
                    #pragma unroll
                    for (int j = 0; j < 4; j++)
                        gll16(vsn + (j * 256 + t) * 8, (void*)&Vs[cur ^ 1][(j * 256 + wbase) * 8]);
                }
                const int k0 = tt * 64;
                short* Pp = P + (w * 2 + pb) * 512;

                // ---- QK^T + exp + P-write ----
                #pragma unroll
                for (int kt = 0; kt < 2; kt++) {
                    f32x4 sc = (f32x4)0.f;
                    #pragma unroll
                    for (int kc = 0; kc < 4; kc++) {
                        const short8 bf = *(const short8*)
                            &Bs[cur][((kc * 4 + g) * 64 + kh * 32 + kt * 16 + c) * 8];
                        sc = __builtin_amdgcn_mfma_f32_16x16x32_bf16(qf[kc], bf, sc, 0, 0, 0);
                    }
                    const int key = k0 + kh * 32 + kt * 16 + c;
                    const float sqkv = grav ? SQb[key] : 0.f;
                    #pragma unroll
                    for (int r = 0; r < 4; r++) {
                        const int qrow = q0 + qh * 16 + 4 * g + r;
                        float p = 0.f;
                        if (key <= qrow) {
                            if (grav) {
                                float d2 = sqq[r] + sqkv - 2.f * sc[r];
                                d2 = fmaxf(d2, 0.f);
                                p = __builtin_amdgcn_exp2f(d2 * CG);
                            } else {
                                p = __builtin_amdgcn_exp2f(sc[r] * CL);
                            }
                        }
                        const short ph = f2bf(p);
                        rsum[r] += bf2f(ph);
                        const int row = 4 * g + r;
                        Pp[row * 32 + ((kt * 16 + c) ^ (g << 3))] = ph;
                    }
                }

                // ---- PV ----
                const short8 pf = *(const short8*)&Pp[c * 32 + 8 * (g ^ ((c >> 2) & 3))];
                #pragma unroll
                for (int dt = 0; dt < 8; dt++) {
                    const short8 vf = *(const short8*)
                        &Vs[cur][((kh * 4 + g) * 128 + dt * 16 + c) * 8];
                    acc[dt] = __builtin_amdgcn_mfma_f32_16x16x32_bf16(pf, vf, acc[dt], 0, 0, 0);
                }
            }
        }

        // ---- intra-block merge (Obuf aliases Bs, dead now) ----
        __syncthreads();
        for (int i = t; i < 32 * 132; i += 256) Obuf[i] = 0.f;
        if (t < 32) Rs[t] = 0.f;
        __syncthreads();

        #pragma unroll
        for (int dt = 0; dt < 8; dt++)
            #pragma unroll
            for (int r = 0; r < 4; r++)
                atomicAdd(&Obuf[(qh * 16 + 4 * g + r) * 132 + dt * 16 + c], acc[dt][r]);

        #pragma unroll
        for (int r = 0; r < 4; r++) {
            float v = rsum[r];
            v += __shfl_xor(v, 1); v += __shfl_xor(v, 2);
            v += __shfl_xor(v, 4); v += __shfl_xor(v, 8);
            rsum[r] = v;
        }
        if (c == 0) {
            #pragma unroll
            for (int r = 0; r < 4; r++)
                atomicAdd(&Rs[qh * 16 + 4 * g + r], rsum[r]);
        }
        __syncthreads();

        // ---- 2-way cross-block merge via global atomics ----
        float* Op = (grav ? OG : OL) + fb + (size_t)q0 * 128;
        #pragma unroll
        for (int i = 0; i < 16; i++) {
            const int v2 = t + 256 * i;   // 0..4095
            atomicAdd(&Op[v2], Obuf[(v2 >> 7) * 132 + (v2 & 127)]);
        }
        if (t < 32) atomicAdd(&(grav ? GS : LS)[b * SEQ + q0 + t], Rs[t]);
    }
}

// ---------------- finalize: out = 0.7*OL/LS + 0.3*OG/(GS+1e-8) ----------------
__global__ __launch_bounds__(256) void finalize_kernel(
    float* __restrict__ out, const float* __restrict__ OG,
    const float* __restrict__ LS, const float* __restrict__ GS)
{
    const int i4 = blockIdx.x * 256 + threadIdx.x;
    float4 o = ((float4*)out)[i4];
    const float4 gv = ((const float4*)OG)[i4];
    const int row = i4 >> 5;
    const float wl = 0.7f / LS[row];
    const float wg = 0.3f / (GS[row] + 1e-8f);
    o.x = o.x * wl + gv.x * wg;
    o.y = o.y * wl + gv.y * wg;
    o.z = o.z * wl + gv.z * wg;
    o.w = o.w * wl + gv.w * wg;
    ((float4*)out)[i4] = o;
}

extern "C" void kernel_launch(void* const* d_in, const int* in_sizes, int n_in,
                              void* d_out, int out_size, void* d_ws, size_t ws_size,
                              hipStream_t stream) {
    const float* x  = (const float*)d_in[0];
    const float* Wq = (const float*)d_in[1];
    const float* Wk = (const float*)d_in[2];
    const float* Wv = (const float*)d_in[3];
    const float* Lg = (const float*)d_in[4];

    char* ws = (char*)d_ws;
    short* Qh  = (short*)(ws + 0);         // frag-linear
    short* Kh  = (short*)(ws + 2097152);   // frag-linear
    short* Vh  = (short*)(ws + 4194304);   // row-major (vt input)
    short* Yh  = (short*)(ws + 6291456);   // frag-linear
    short* Vf  = (short*)(ws + 8388608);   // V transposed-frag
    short* Wt2 = (short*)(ws + 10485760);
    float* SQv = (float*)(ws + 11272192);
    float* LS  = (float*)(ws + 11304960);
    float* GS  = (float*)(ws + 11337728);
    float* OG  = (float*)(ws + 11370496);
    float* OL  = (float*)d_out;

    hipMemsetAsync(d_out, 0, 4194304, stream);
    hipMemsetAsync((void*)LS, 0, 65536, stream);
    hipMemsetAsync((void*)OG, 0, 4194304, stream);

    wt_kernel<<<48, 256, 0, stream>>>(Wq, Wk, Wv, Wt2);
    proj_kernel<<<768, 256, 0, stream>>>(x, Wt2, Qh, Kh, Vh);
    y_kernel<<<512, 256, 0, stream>>>(Kh, Lg, Yh, SQv);
    vt_kernel<<<256, 256, 0, stream>>>(Vh, Vf);
    attn_kernel<<<512, 256, 0, stream>>>(Qh, Kh, Yh, Vf, SQv, OL, OG, LS, GS);
    finalize_kernel<<<1024, 256, 0, stream>>>((float*)d_out, OG, LS, GS);
}